// Round 1
// baseline (196.191 us; speedup 1.0000x reference)
//
#include <hip/hip_runtime.h>
#include <math.h>

#define NB 8
#define NN 1024
#define NI 64
#define NO 32
#define NH 4
#define NEGINF (-1e30f)

// ---------------- Kernel 1: projection + attention scores ----------------
// One block per (b,n). 128 threads: thread t -> h = t>>5, o = t&31.
__global__ __launch_bounds__(128) void gat_proj(
    const float* __restrict__ x,        // [B,N,I]
    const float* __restrict__ beta,     // [H]
    const float* __restrict__ weight,   // [H,I,O]
    const float* __restrict__ attn_src, // [H,O]
    const float* __restrict__ attn_dst, // [H,O]
    const float* __restrict__ bias,     // [H,O]
    const float* __restrict__ prior,    // [B,N]
    float* __restrict__ proj,           // [B,H,N,O]
    float* __restrict__ src_s,          // [B,H,N]
    float* __restrict__ dst_s,          // [B,H,N]
    float* __restrict__ gp)             // [B,H,N] = softplus(beta[h])*prior[b,s]
{
    __shared__ float xrow[NI];
    const int bn = blockIdx.x;
    const int b = bn >> 10, n = bn & (NN - 1);
    const int t = threadIdx.x;
    if (t < NI) xrow[t] = x[bn * NI + t];
    __syncthreads();
    const int h = t >> 5, o = t & 31;
    float acc = bias[h * NO + o];
    const float* wp = weight + h * NI * NO + o;
    #pragma unroll
    for (int i = 0; i < NI; ++i) acc = fmaf(xrow[i], wp[i * NO], acc);
    const int bh = b * NH + h;
    proj[((size_t)bh * NN + n) * NO + o] = acc;
    float ps = acc * attn_src[h * NO + o];
    float pd = acc * attn_dst[h * NO + o];
    #pragma unroll
    for (int m = 16; m >= 1; m >>= 1) {
        ps += __shfl_xor(ps, m, 64);
        pd += __shfl_xor(pd, m, 64);
    }
    if (o == 0) {
        src_s[bh * NN + n] = ps;
        dst_s[bh * NN + n] = pd;
    }
    if (t < NH) {
        float bx = beta[t];
        float sp = fmaxf(bx, 0.f) + log1pf(expf(-fabsf(bx)));  // stable softplus
        gp[(b * NH + t) * NN + n] = sp * prior[b * NN + n];
    }
}

// ---------------- Kernel 2: fused masked softmax + aggregation ----------------
// One block per (b, h, tile of 64 dst rows). 128 threads.
// Phase C: thread t owns rows d0..d0+3 (d0 = (t>>3)*4), cols o0..o0+3 (o0=(t&7)*4).
// Online-softmax state: row dr = t>>1 owned by thread pair (t, t^1).
#define TD 64
#define TS 64
#define PPAD 65   // 65 % 32 == 1 -> conflict-free-ish scalar access both ways
#define VPAD 36   // multiple of 4 (float4-aligned), 36 % 32 == 4 spreads banks

__global__ __launch_bounds__(128) void gat_attn(
    const int* __restrict__ adj,     // [N,N]
    const float* __restrict__ proj,  // [B,H,N,O]
    const float* __restrict__ src_s,
    const float* __restrict__ dst_s,
    const float* __restrict__ gp,
    float* __restrict__ out)         // [B,N,H*O]
{
    __shared__ __align__(16) float ptile[TD * PPAD];
    __shared__ __align__(16) float vtile[TS * VPAD];
    __shared__ float srcv[TS], gpv[TS], dstt[TD], alphat[TD], lt[TD];

    const int t = threadIdx.x;
    const int dbase = blockIdx.x * TD;
    const int h = blockIdx.y, b = blockIdx.z;
    const int bh = b * NH + h;
    const float* projbh = proj + (size_t)bh * NN * NO;
    const float* srcp = src_s + bh * NN;
    const float* gpp  = gp + bh * NN;

    if (t < TD) dstt[t] = dst_s[bh * NN + dbase + t];

    const int og = t & 7, dg = t >> 3;
    const int o0 = og * 4, d0 = dg * 4;
    float acc[4][4];
    #pragma unroll
    for (int i = 0; i < 4; ++i)
        #pragma unroll
        for (int j = 0; j < 4; ++j) acc[i][j] = 0.f;

    const int dr = t >> 1, half = t & 1, sbb = half * 32;
    float m_row = NEGINF, l_row = 0.f;

    for (int s0 = 0; s0 < NN; s0 += TS) {
        __syncthreads();  // previous phase C done before restaging
        if (t < TS) { srcv[t] = srcp[s0 + t]; gpv[t] = gpp[s0 + t]; }
        #pragma unroll
        for (int k = 0; k < (TS * NO) / 128; ++k) {  // V tile, coalesced
            int e = t + k * 128;
            int s = e >> 5, o = e & 31;
            vtile[s * VPAD + o] = projbh[(size_t)(s0 + s) * NO + o];
        }
        __syncthreads();
        // Phase B1: masked leaky-relu scores -> ptile[d][s] (coalesced adj read)
        #pragma unroll
        for (int k = 0; k < (TD * TS) / 128; ++k) {
            int e = t + k * 128;
            int d = e >> 6, s = e & 63;
            int a = adj[(size_t)(dbase + d) * NN + (s0 + s)];
            float sc = dstt[d] + srcv[s];
            sc = sc > 0.f ? sc : 0.2f * sc;   // leaky_relu 0.2
            sc += gpv[s];
            ptile[d * PPAD + s] = a ? sc : NEGINF;
        }
        __syncthreads();
        // Phase B2: online softmax update; 2 threads per row
        float mt = NEGINF;
        #pragma unroll
        for (int j = 0; j < 32; ++j) mt = fmaxf(mt, ptile[dr * PPAD + sbb + j]);
        mt = fmaxf(mt, __shfl_xor(mt, 1, 64));
        const float m_new = fmaxf(m_row, mt);
        const float alpha = __expf(m_row - m_new);  // 1.0 if both still NEGINF
        float psum = 0.f;
        #pragma unroll
        for (int j = 0; j < 32; ++j) {
            float sc = ptile[dr * PPAD + sbb + j];
            float p = (sc < -1e29f) ? 0.f : __expf(sc - m_new);  // masked -> 0
            ptile[dr * PPAD + sbb + j] = p;
            psum += p;
        }
        psum += __shfl_xor(psum, 1, 64);
        l_row = l_row * alpha + psum;
        m_row = m_new;
        if (half == 0) alphat[dr] = alpha;
        __syncthreads();
        // Phase C: acc rescale + outer-product accumulation
        #pragma unroll
        for (int di = 0; di < 4; ++di) {
            const float a = alphat[d0 + di];
            #pragma unroll
            for (int oi = 0; oi < 4; ++oi) acc[di][oi] *= a;
        }
        #pragma unroll 8
        for (int s = 0; s < TS; ++s) {
            const float4 vv = *(const float4*)&vtile[s * VPAD + o0];
            #pragma unroll
            for (int di = 0; di < 4; ++di) {
                const float p = ptile[(d0 + di) * PPAD + s];
                acc[di][0] = fmaf(p, vv.x, acc[di][0]);
                acc[di][1] = fmaf(p, vv.y, acc[di][1]);
                acc[di][2] = fmaf(p, vv.z, acc[di][2]);
                acc[di][3] = fmaf(p, vv.w, acc[di][3]);
            }
        }
    }
    if (half == 0) lt[dr] = l_row;
    __syncthreads();
    const float eps = 1.1920929e-07f;  // float32 machine eps
    #pragma unroll
    for (int di = 0; di < 4; ++di) {
        const float inv = 1.f / fmaxf(lt[d0 + di], eps);
        float4 r;
        r.x = acc[di][0] * inv; r.y = acc[di][1] * inv;
        r.z = acc[di][2] * inv; r.w = acc[di][3] * inv;
        *(float4*)&out[((size_t)(b * NN + dbase + d0 + di)) * (NH * NO) + h * NO + o0] = r;
    }
}

extern "C" void kernel_launch(void* const* d_in, const int* in_sizes, int n_in,
                              void* d_out, int out_size, void* d_ws, size_t ws_size,
                              hipStream_t stream) {
    (void)in_sizes; (void)n_in; (void)out_size; (void)ws_size;
    const float* x        = (const float*)d_in[0];
    const int*   adj      = (const int*)d_in[1];
    const float* prior    = (const float*)d_in[2];
    const float* beta     = (const float*)d_in[3];
    const float* weight   = (const float*)d_in[4];
    const float* attn_src = (const float*)d_in[5];
    const float* attn_dst = (const float*)d_in[6];
    const float* bias     = (const float*)d_in[7];
    float* out = (float*)d_out;

    float* ws    = (float*)d_ws;
    float* proj  = ws;                                   // B*H*N*O = 1048576
    float* src_s = proj + (size_t)NB * NH * NN * NO;     // B*H*N   =   32768
    float* dst_s = src_s + NB * NH * NN;
    float* gpb   = dst_s + NB * NH * NN;

    hipLaunchKernelGGL(gat_proj, dim3(NB * NN), dim3(128), 0, stream,
                       x, beta, weight, attn_src, attn_dst, bias, prior,
                       proj, src_s, dst_s, gpb);
    hipLaunchKernelGGL(gat_attn, dim3(NN / TD, NH, NB), dim3(128), 0, stream,
                       adj, proj, src_s, dst_s, gpb, out);
}

// Round 2
// 103.649 us; speedup vs baseline: 1.8928x; 1.8928x over previous
//
#include <hip/hip_runtime.h>
#include <math.h>

#define NB 8
#define NN 1024
#define NI 64
#define NO 32
#define NH 4
#define NEGINF (-1e30f)

typedef _Float16 half8 __attribute__((ext_vector_type(8)));
typedef _Float16 half4v __attribute__((ext_vector_type(4)));
typedef float floatx4 __attribute__((ext_vector_type(4)));

// ---------------- Kernel 0: pack adj int32 -> byte ----------------
__global__ __launch_bounds__(256) void k_pack(const int* __restrict__ adj,
                                              unsigned char* __restrict__ adjb) {
    const int i = blockIdx.x * 256 + threadIdx.x;   // 262144 int4 groups
    const int4 v = ((const int4*)adj)[i];
    unsigned int p = (v.x ? 1u : 0u) | ((v.y ? 1u : 0u) << 8) |
                     ((v.z ? 1u : 0u) << 16) | ((v.w ? 1u : 0u) << 24);
    ((unsigned int*)adjb)[i] = p;
}

// ---------------- Kernel 1: projection + scores ----------------
// grid (32 ntiles, 8 b), 256 threads. Thread: o4=t&7 (4 o's), h=(t>>3)&3,
// ng=t>>5 (4 consecutive n's). Register tile 4n x 4o.
__global__ __launch_bounds__(256) void k_proj(
    const float* __restrict__ x, const float* __restrict__ beta,
    const float* __restrict__ weight, const float* __restrict__ attn_src,
    const float* __restrict__ attn_dst, const float* __restrict__ bias,
    const float* __restrict__ prior,
    _Float16* __restrict__ projT,   // [B,H,O,N] fp16
    float* __restrict__ src_s, float* __restrict__ dst_s, float* __restrict__ gp)
{
    __shared__ __align__(16) float xs[32 * 64];       // [n][i]
    __shared__ __align__(16) float ws[4 * 64 * 36];   // [h][i][o pad 36]
    const int t = threadIdx.x;
    const int ntile = blockIdx.x, b = blockIdx.y;
    const int n0b = ntile * 32;
    {   // stage x tile (coalesced)
        const float4* xsrc = (const float4*)(x + ((size_t)b * NN + n0b) * NI);
        float4* xd = (float4*)xs;
        xd[t] = xsrc[t];
        xd[t + 256] = xsrc[t + 256];
    }
    #pragma unroll
    for (int k = 0; k < 8; ++k) {   // stage weight, padded
        int e = t + k * 256;
        int h = e >> 9, rem = e & 511, i = rem >> 3, o4 = rem & 7;
        float4 wv = *(const float4*)(weight + (h * NI + i) * NO + o4 * 4);
        *(float4*)&ws[h * 2304 + i * 36 + o4 * 4] = wv;
    }
    __syncthreads();

    const int o4 = t & 7, h = (t >> 3) & 3, ng = t >> 5;
    const int o0 = o4 * 4, nl0 = ng * 4;
    float acc[4][4];
    #pragma unroll
    for (int kn = 0; kn < 4; ++kn)
        #pragma unroll
        for (int oo = 0; oo < 4; ++oo) acc[kn][oo] = 0.f;

    for (int i = 0; i < NI; ++i) {
        const float4 wv = *(const float4*)&ws[h * 2304 + i * 36 + o0];
        #pragma unroll
        for (int kn = 0; kn < 4; ++kn) {
            const float xv = xs[(nl0 + kn) * 64 + i];
            acc[kn][0] = fmaf(xv, wv.x, acc[kn][0]);
            acc[kn][1] = fmaf(xv, wv.y, acc[kn][1]);
            acc[kn][2] = fmaf(xv, wv.z, acc[kn][2]);
            acc[kn][3] = fmaf(xv, wv.w, acc[kn][3]);
        }
    }
    const float4 bv  = *(const float4*)(bias + h * NO + o0);
    const float4 asv = *(const float4*)(attn_src + h * NO + o0);
    const float4 adv = *(const float4*)(attn_dst + h * NO + o0);
    const int bh = b * NH + h;
    float ssum[4], dsum[4];
    #pragma unroll
    for (int kn = 0; kn < 4; ++kn) {
        acc[kn][0] += bv.x; acc[kn][1] += bv.y;
        acc[kn][2] += bv.z; acc[kn][3] += bv.w;
        ssum[kn] = acc[kn][0]*asv.x + acc[kn][1]*asv.y + acc[kn][2]*asv.z + acc[kn][3]*asv.w;
        dsum[kn] = acc[kn][0]*adv.x + acc[kn][1]*adv.y + acc[kn][2]*adv.z + acc[kn][3]*adv.w;
    }
    // store projT fp16 (4 consecutive n per store)
    #pragma unroll
    for (int oo = 0; oo < 4; ++oo) {
        half4v hv;
        hv[0] = (_Float16)acc[0][oo]; hv[1] = (_Float16)acc[1][oo];
        hv[2] = (_Float16)acc[2][oo]; hv[3] = (_Float16)acc[3][oo];
        *(half4v*)(projT + ((size_t)(bh * NO + o0 + oo)) * NN + n0b + nl0) = hv;
    }
    // reduce scores across the 8 o4-lanes
    #pragma unroll
    for (int msk = 1; msk <= 4; msk <<= 1) {
        #pragma unroll
        for (int kn = 0; kn < 4; ++kn) {
            ssum[kn] += __shfl_xor(ssum[kn], msk, 64);
            dsum[kn] += __shfl_xor(dsum[kn], msk, 64);
        }
    }
    if (o4 == 0) {
        const float bx = beta[h];
        const float sp = fmaxf(bx, 0.f) + log1pf(__expf(-fabsf(bx)));
        #pragma unroll
        for (int kn = 0; kn < 4; ++kn) {
            const int n = n0b + nl0 + kn;
            src_s[bh * NN + n] = ssum[kn];
            dst_s[bh * NN + n] = dsum[kn];
            gp[bh * NN + n] = sp * prior[b * NN + n];
        }
    }
}

// ---------------- Kernel 2: flash attention with f16 MFMA ----------------
// grid (16 dtiles, 4 h, 8 b), 256 threads = 4 waves, wave owns 16 dst rows.
// A-frag: A[m=lane&15][k=quad*8+j]; B-frag: B[k=quad*8+j][n=lane&15];
// C: row=quad*4+reg, col=lane&15.
#define SPH 512          // s per phase
#define SP  520          // vt row pad (halfs); 520*2=1040B, 16B-aligned

__global__ __launch_bounds__(256) void k_attn(
    const unsigned char* __restrict__ adjb,  // [N][N] bytes
    const _Float16* __restrict__ projT,      // [B,H,O,N]
    const float* __restrict__ src_s, const float* __restrict__ dst_s,
    const float* __restrict__ gp,
    float* __restrict__ out)                 // [B,N,H*O]
{
    __shared__ __align__(16) _Float16 vt[NO * SP];
    __shared__ __align__(16) float srcs[NN];
    __shared__ __align__(16) float gps[NN];
    const int t = threadIdx.x;
    const int lane = t & 63, wave = t >> 6;
    const int dtile = blockIdx.x, h = blockIdx.y, b = blockIdx.z;
    const int bh = b * NH + h;
    {   // stage src scores + gain*prior (full 1024 each)
        ((float4*)srcs)[t] = ((const float4*)(src_s + bh * NN))[t];
        ((float4*)gps)[t]  = ((const float4*)(gp + bh * NN))[t];
    }
    const int m = lane & 15, quad = lane >> 4;
    const int d = dtile * 64 + wave * 16 + m;
    const float dreg = dst_s[bh * NN + d];
    const unsigned char* adjr = adjb + (size_t)d * NN;
    const _Float16* ptrow = projT + (size_t)bh * NO * NN;

    floatx4 acc0 = {0.f, 0.f, 0.f, 0.f}, acc1 = {0.f, 0.f, 0.f, 0.f};
    float m_s = NEGINF, l_s = 0.f;
    uint2 apre = *(const uint2*)(adjr + quad * 8);   // prefetch step 0

    for (int ph = 0; ph < 2; ++ph) {
        #pragma unroll
        for (int rr = 0; rr < 8; ++rr) {   // stage V^T tile: 32 rows x 512 s
            const int o = wave * 8 + rr;
            *(half8*)&vt[o * SP + lane * 8] =
                *(const half8*)(ptrow + (size_t)o * NN + ph * SPH + lane * 8);
        }
        __syncthreads();
        for (int st = 0; st < 16; ++st) {
            const int gs = ph * 16 + st;
            const uint2 acur = apre;
            if (gs < 31) apre = *(const uint2*)(adjr + (gs + 1) * 32 + quad * 8);
            const int sg = gs * 32 + quad * 8;
            const float4 s_lo = *(const float4*)&srcs[sg];
            const float4 s_hi = *(const float4*)&srcs[sg + 4];
            const float4 g_lo = *(const float4*)&gps[sg];
            const float4 g_hi = *(const float4*)&gps[sg + 4];
            const float sv[8] = {s_lo.x, s_lo.y, s_lo.z, s_lo.w,
                                 s_hi.x, s_hi.y, s_hi.z, s_hi.w};
            const float gv[8] = {g_lo.x, g_lo.y, g_lo.z, g_lo.w,
                                 g_hi.x, g_hi.y, g_hi.z, g_hi.w};
            float scm[8], mkf[8];
            #pragma unroll
            for (int j = 0; j < 8; ++j) {
                const unsigned int bit =
                    ((j < 4 ? (acur.x >> (8 * j)) : (acur.y >> (8 * (j - 4)))) & 1u);
                const float ts = dreg + sv[j];
                const float lk = fmaxf(ts, 0.f) + 0.2f * fminf(ts, 0.f);
                const float sc = lk + gv[j];
                mkf[j] = bit ? 1.f : 0.f;
                scm[j] = bit ? sc : NEGINF;
            }
            float mq = scm[0];
            #pragma unroll
            for (int j = 1; j < 8; ++j) mq = fmaxf(mq, scm[j]);
            mq = fmaxf(mq, __shfl_xor(mq, 16, 64));
            mq = fmaxf(mq, __shfl_xor(mq, 32, 64));
            const float m_new = fmaxf(m_s, mq);
            const float alpha = __expf(m_s - m_new);
            m_s = m_new;
            float p[8], psum = 0.f;
            #pragma unroll
            for (int j = 0; j < 8; ++j) {
                p[j] = mkf[j] * __expf(scm[j] - m_new);
                psum += p[j];
            }
            psum += __shfl_xor(psum, 16, 64);
            psum += __shfl_xor(psum, 32, 64);
            l_s = l_s * alpha + psum;
            #pragma unroll
            for (int r = 0; r < 4; ++r) {   // rescale accumulators
                const float ar = __shfl(alpha, quad * 4 + r, 64);
                acc0[r] *= ar; acc1[r] *= ar;
            }
            half8 af;
            #pragma unroll
            for (int j = 0; j < 8; ++j) af[j] = (_Float16)p[j];
            const int sl = st * 32 + quad * 8;
            const half8 b0 = *(const half8*)&vt[m * SP + sl];
            const half8 b1 = *(const half8*)&vt[(16 + m) * SP + sl];
            acc0 = __builtin_amdgcn_mfma_f32_16x16x32_f16(af, b0, acc0, 0, 0, 0);
            acc1 = __builtin_amdgcn_mfma_f32_16x16x32_f16(af, b1, acc1, 0, 0, 0);
        }
        __syncthreads();
    }
    #pragma unroll
    for (int r = 0; r < 4; ++r) {
        const int row = quad * 4 + r;
        const float lr = __shfl(l_s, row, 64);
        const float inv = 1.f / fmaxf(lr, 1.1920929e-07f);
        float* go = out + ((size_t)(b * NN + dtile * 64 + wave * 16 + row)) * (NH * NO) + h * NO;
        go[m] = acc0[r] * inv;
        go[16 + m] = acc1[r] * inv;
    }
}

extern "C" void kernel_launch(void* const* d_in, const int* in_sizes, int n_in,
                              void* d_out, int out_size, void* d_ws, size_t ws_size,
                              hipStream_t stream) {
    (void)in_sizes; (void)n_in; (void)out_size; (void)ws_size;
    const float* x        = (const float*)d_in[0];
    const int*   adj      = (const int*)d_in[1];
    const float* prior    = (const float*)d_in[2];
    const float* beta     = (const float*)d_in[3];
    const float* weight   = (const float*)d_in[4];
    const float* attn_src = (const float*)d_in[5];
    const float* attn_dst = (const float*)d_in[6];
    const float* bias     = (const float*)d_in[7];
    float* out = (float*)d_out;

    _Float16* projT = (_Float16*)d_ws;                         // 2 MB
    float* src_s = (float*)((char*)d_ws + (1 << 21));          // 128 KB
    float* dst_s = src_s + NB * NH * NN;
    float* gpb   = dst_s + NB * NH * NN;
    unsigned char* adjb = (unsigned char*)(gpb + NB * NH * NN); // 1 MB

    hipLaunchKernelGGL(k_pack, dim3(1024), dim3(256), 0, stream, adj, adjb);
    hipLaunchKernelGGL(k_proj, dim3(32, 8), dim3(256), 0, stream,
                       x, beta, weight, attn_src, attn_dst, bias, prior,
                       projT, src_s, dst_s, gpb);
    hipLaunchKernelGGL(k_attn, dim3(16, 4, 8), dim3(256), 0, stream,
                       adjb, projT, src_s, dst_s, gpb, out);
}